// Round 1
// baseline (5263.239 us; speedup 1.0000x reference)
//
#include <hip/hip_runtime.h>

// (T,B,I,H) = (1024, 64, 512, 512)
#define T_STEPS 1024
#define BATCH   64
#define IN_F    512
#define HID     512
#define G3      1536
#define M_ROWS  (T_STEPS * BATCH)

// hbuf: [2 ping-pong][4 chunks][16 seqs][256 colpairs] u64
#define HB_U64  (2 * 4 * 16 * 256)

typedef _Float16 v8h  __attribute__((ext_vector_type(8)));
typedef float    v4f  __attribute__((ext_vector_type(4)));

// ---------------------------------------------------------------------------
// gx = x * w_ih^T + b_ih -> f16 [65536][1536]   (unchanged, passing)
// ---------------------------------------------------------------------------
#define BM 64
#define BN 128
#define BK 32
#define LDP 40

__global__ __launch_bounds__(256) void gemm_gx(
    const float* __restrict__ X, const float* __restrict__ W,
    const float* __restrict__ bias, _Float16* __restrict__ C) {
  __shared__ _Float16 As[BM][LDP];
  __shared__ _Float16 Bs[BN][LDP];
  const int tid  = threadIdx.x;
  const int lane = tid & 63;
  const int wave = tid >> 6;
  const int m0 = blockIdx.y * BM;
  const int n0 = blockIdx.x * BN;

  v4f acc[8];
#pragma unroll
  for (int i = 0; i < 8; ++i) acc[i] = (v4f){0.f, 0.f, 0.f, 0.f};

  const int srow  = tid >> 2;
  const int kpart = (tid & 3) * 8;
  const int fr = lane & 15;
  const int ko = (lane >> 4) * 8;

  for (int kc = 0; kc < IN_F; kc += BK) {
    {
      const float* s = X + (size_t)(m0 + srow) * IN_F + kc + kpart;
      float4 a = *(const float4*)s;
      float4 b = *(const float4*)(s + 4);
      v8h o = {(_Float16)a.x, (_Float16)a.y, (_Float16)a.z, (_Float16)a.w,
               (_Float16)b.x, (_Float16)b.y, (_Float16)b.z, (_Float16)b.w};
      *(v8h*)&As[srow][kpart] = o;
    }
#pragma unroll
    for (int r = 0; r < 2; ++r) {
      const float* s = W + (size_t)(n0 + r * 64 + srow) * IN_F + kc + kpart;
      float4 a = *(const float4*)s;
      float4 b = *(const float4*)(s + 4);
      v8h o = {(_Float16)a.x, (_Float16)a.y, (_Float16)a.z, (_Float16)a.w,
               (_Float16)b.x, (_Float16)b.y, (_Float16)b.z, (_Float16)b.w};
      *(v8h*)&Bs[r * 64 + srow][kpart] = o;
    }
    __syncthreads();
    v8h af = *(const v8h*)&As[wave * 16 + fr][ko];
#pragma unroll
    for (int nt = 0; nt < 8; ++nt) {
      v8h bf = *(const v8h*)&Bs[nt * 16 + fr][ko];
      acc[nt] = __builtin_amdgcn_mfma_f32_16x16x32_f16(af, bf, acc[nt], 0, 0, 0);
    }
    __syncthreads();
  }

  const int rq = lane >> 4;
#pragma unroll
  for (int nt = 0; nt < 8; ++nt) {
    const int gcol = n0 + nt * 16 + fr;
    const float bv = bias[gcol];
#pragma unroll
    for (int r = 0; r < 4; ++r) {
      const int grow = m0 + wave * 16 + rq * 4 + r;
      C[(size_t)grow * G3 + gcol] = (_Float16)(acc[nt][r] + bv);
    }
  }
}

__global__ void zero_hbuf(unsigned long long* h) {
  const int i = blockIdx.x * 256 + threadIdx.x;
  if (i < HB_U64) h[i] = 0ull;
}

// Zero-pad out rows with t >= len[b] (scan no longer writes them).
// Does NOT touch the h_last row at t == T_STEPS.
__global__ __launch_bounds__(256) void zero_out_tail(const int* __restrict__ lens,
                                                     float* __restrict__ out) {
  __shared__ int slen[BATCH];
  if (threadIdx.x < BATCH) slen[threadIdx.x] = lens[threadIdx.x];
  __syncthreads();
  for (int row = blockIdx.x; row < T_STEPS * BATCH; row += gridDim.x) {
    const int t = row >> 6;
    const int b = row & 63;
    if (t < slen[b]) continue;
    float2* dst = (float2*)(out + (size_t)row * HID);
    dst[threadIdx.x] = make_float2(0.f, 0.f);  // 256 thr x float2 = 512 floats
  }
}

// Raw barrier: LDS ordering only (lgkmcnt), NO vmcnt drain -> poll loads
// issued before the barrier stay in flight across it.
static __device__ __forceinline__ void wg_barrier() {
  asm volatile("s_waitcnt lgkmcnt(0)" ::: "memory");
  __builtin_amdgcn_s_barrier();
  asm volatile("" ::: "memory");
}

// ---------------------------------------------------------------------------
// Interleaved persistent-weight GRU scan.
// 32 WGs = 16 slices x 2 sets. Set s owns seq ranks [32s, 32s+32), split into
// two 16-seq clusters by even/odd rank (both glens ~max -> paired to the end).
// Each WG (256 thr): waves 0-2 = gate matvecs (reg-resident weight B-frags,
// shared by both clusters), wave 3 helps land/epilogue. Per timestep the two
// clusters' phases alternate; poll loads for the NEXT phase are issued at the
// top of the current phase and fly across raw barriers, so exchanged h is
// ~1 full phase old when landed (hides agent-scope visibility latency).
// Exchange protocol (tag-in-data u64, relaxed agent, ping-pong) unchanged.
// ---------------------------------------------------------------------------
#define PHASE(C)                                                               \
  {                                                                            \
    const int chunk = set * 2 + C;                                             \
    /* ---- land h_C(t): polls were issued one phase ago ---- */               \
    if (t > 0) {                                                               \
      const unsigned want = (unsigned)t;                                       \
      const unsigned long long* src =                                          \
          hbuf + (((size_t)((t & 1) * 4 + chunk)) << 12);                      \
      unsigned pend = 0xffffu;                                                 \
      while (true) {                                                           \
        unsigned np = 0u;                                                      \
        _Pragma("unroll") for (int k = 0; k < 16; ++k) {                       \
          if (pend & (1u << k)) {                                              \
            if ((unsigned)(got[k] >> 32) >= want) {                            \
              *(unsigned*)&h16f[C * (16 * 520) + k * 520 + tid * 2] =          \
                  (unsigned)got[k];                                            \
            } else np |= (1u << k);                                            \
          }                                                                    \
        }                                                                      \
        if (!np) break;                                                        \
        __builtin_amdgcn_s_sleep(1);                                           \
        _Pragma("unroll") for (int k = 0; k < 16; ++k) {                       \
          if (np & (1u << k))                                                  \
            got[k] = __hip_atomic_load(src + k * 256 + tid, __ATOMIC_RELAXED,  \
                                       __HIP_MEMORY_SCOPE_AGENT);              \
        }                                                                      \
        pend = np;                                                             \
      }                                                                        \
    }                                                                          \
    /* ---- issue polls for the next phase (kept in flight) ---- */            \
    {                                                                          \
      int tn, cn;                                                              \
      if (C == 0) {                                                            \
        if (t < glen1) { tn = t; cn = 1; } else { tn = t + 1; cn = 0; }        \
      } else {                                                                 \
        if (t + 1 < glen0) { tn = t + 1; cn = 0; } else { tn = t + 1; cn = 1; }\
      }                                                                        \
      const int gl = (cn == 0) ? glen0 : glen1;                                \
      if (tn >= 1 && tn < gl) {                                                \
        const unsigned long long* srcn =                                       \
            hbuf + (((size_t)((tn & 1) * 4 + set * 2 + cn)) << 12);            \
        _Pragma("unroll") for (int k = 0; k < 16; ++k)                         \
          got[k] = __hip_atomic_load(srcn + k * 256 + tid, __ATOMIC_RELAXED,   \
                                     __HIP_MEMORY_SCOPE_AGENT);               \
      }                                                                        \
    }                                                                          \
    wg_barrier(); /* h16 landing visible to matvec; polls stay in flight */    \
    /* ---- matvec: gh = h_C @ W^T for this wave's gate, 32 cols ---- */       \
    if (w < 3) {                                                               \
      const _Float16* hb = h16f + C * (16 * 520) + arow * 520 + ak;            \
      v4f a0a = (v4f){0.f, 0.f, 0.f, 0.f}, a0b = a0a, a1a = a0a, a1b = a0a;    \
      _Pragma("unroll") for (int kt = 0; kt < 8; ++kt) {                       \
        v8h af = *(const v8h*)(hb + kt * 32);                                  \
        a0a = __builtin_amdgcn_mfma_f32_16x16x32_f16(af, bw0[kt], a0a, 0,0,0); \
        a1a = __builtin_amdgcn_mfma_f32_16x16x32_f16(af, bw1[kt], a1a, 0,0,0); \
      }                                                                        \
      _Pragma("unroll") for (int kt = 8; kt < 16; ++kt) {                      \
        v8h af = *(const v8h*)(hb + kt * 32);                                  \
        a0b = __builtin_amdgcn_mfma_f32_16x16x32_f16(af, bw0[kt], a0b, 0,0,0); \
        a1b = __builtin_amdgcn_mfma_f32_16x16x32_f16(af, bw1[kt], a1b, 0,0,0); \
      }                                                                        \
      v4f acc0 = a0a + a0b;                                                    \
      v4f acc1 = a1a + a1b;                                                    \
      const int col = lane & 15;                                               \
      const int sg  = lane >> 4;                                               \
      *(v4f*)&ghl[(w * 32 + col) * 20 + sg * 4]      = acc0;                   \
      *(v4f*)&ghl[(w * 32 + 16 + col) * 20 + sg * 4] = acc1;                   \
    }                                                                          \
    wg_barrier(); /* ghl visible to epilogue */                                \
    /* ---- epilogue: 256 thr, one (seq, colpair) each ---- */                 \
    {                                                                          \
      const float ar0 = ghl[(0 * 32 + ec0) * 20 + eseq];                       \
      const float ar1 = ghl[(0 * 32 + ec0 + 1) * 20 + eseq];                   \
      const float az0 = ghl[(1 * 32 + ec0) * 20 + eseq];                       \
      const float az1 = ghl[(1 * 32 + ec0 + 1) * 20 + eseq];                   \
      const float an0 = ghl[(2 * 32 + ec0) * 20 + eseq];                       \
      const float an1 = ghl[(2 * 32 + ec0 + 1) * 20 + eseq];                   \
      union { unsigned u; _Float16 h[2]; } g0, g1, g2;                         \
      g0.u = pg[C][0]; g1.u = pg[C][1]; g2.u = pg[C][2];                       \
      const int bq = (C == 0) ? b0 : b1;                                       \
      float h0 = hr[C][0], h1 = hr[C][1];                                      \
      if (t < mylen[C]) {                                                      \
        const float r0 = 1.f / (1.f + __expf(-((float)g0.h[0] + ar0 + br0)));  \
        const float z0 = 1.f / (1.f + __expf(-((float)g1.h[0] + az0 + bz0)));  \
        const float p0 = (float)g2.h[0] + r0 * (an0 + bn0);                    \
        const float n0v = 1.f - 2.f / (__expf(2.f * p0) + 1.f);                \
        h0 = (1.f - z0) * n0v + z0 * h0;                                       \
        const float r1 = 1.f / (1.f + __expf(-((float)g0.h[1] + ar1 + br1)));  \
        const float z1 = 1.f / (1.f + __expf(-((float)g1.h[1] + az1 + bz1)));  \
        const float p1 = (float)g2.h[1] + r1 * (an1 + bn1);                    \
        const float n1v = 1.f - 2.f / (__expf(2.f * p1) + 1.f);                \
        h1 = (1.f - z1) * n1v + z1 * h1;                                       \
        hr[C][0] = h0; hr[C][1] = h1;                                          \
        float* o = out + (size_t)t * (BATCH * HID) + (size_t)bq * HID + ej;    \
        *(float2*)o = make_float2(h0, h1);                                     \
      }                                                                        \
      union { unsigned u; _Float16 h[2]; } pk;                                 \
      pk.h[0] = (_Float16)h0; pk.h[1] = (_Float16)h1;                          \
      const unsigned long long pv =                                            \
          ((unsigned long long)(unsigned)(t + 1) << 32) | pk.u;                \
      const size_t di = (((size_t)(((t + 1) & 1) * 4 + chunk)) << 12) +        \
                        (size_t)eseq * 256 + slice * 16 + (tid & 15);          \
      __hip_atomic_store(hbuf + di, pv, __ATOMIC_RELAXED,                      \
                         __HIP_MEMORY_SCOPE_AGENT);                            \
      const int gcl = (C == 0) ? glen0 : glen1;                                \
      const int tn2 = (t + 1 < gcl) ? t + 1 : t;                               \
      const _Float16* gxr = gx + ((size_t)tn2 * BATCH + bq) * G3 + ej;         \
      pg[C][0] = *(const unsigned*)gxr;                                        \
      pg[C][1] = *(const unsigned*)(gxr + 512);                                \
      pg[C][2] = *(const unsigned*)(gxr + 1024);                               \
    }                                                                          \
  }

__global__ __launch_bounds__(256, 1) void gru_scan3(
    const _Float16* __restrict__ gx, const float* __restrict__ whh,
    const int* __restrict__ lens, const float* __restrict__ bhh,
    float* __restrict__ out, unsigned long long* hbuf) {
  const int bid   = blockIdx.x;
  const int slice = bid & 15;
  const int set   = bid >> 4;
  const int tid  = threadIdx.x;
  const int lane = tid & 63;
  const int w    = tid >> 6;    // waves 0-2: gates (r,z,n); wave 3: helper

  __shared__ __align__(16) _Float16 h16f[2 * 16 * 520];  // [cluster][seq16][512+pad]
  __shared__ __align__(16) float ghl[3 * 32 * 20];       // [gate][col][seq16+pad]
  __shared__ int sgl[2];

  if (tid == 0) { sgl[0] = 0; sgl[1] = 0; }
  for (int i = tid; i < (2 * 16 * 520) / 2; i += 256) ((unsigned*)h16f)[i] = 0u;

  // ---- persistent weight B-frags: wave w = gate, rows slice*32 + [0,32)
  v8h bw0[16], bw1[16];
  if (w < 3) {
    const int r15 = lane & 15;
    const int k8  = (lane >> 4) * 8;
    const float* p0 = whh + (size_t)(w * 512 + slice * 32 + r15) * HID + k8;
    const float* p1 = p0 + 16 * HID;
#pragma unroll
    for (int kt = 0; kt < 16; ++kt) {
      float4 a = *(const float4*)(p0 + kt * 32);
      float4 b = *(const float4*)(p0 + kt * 32 + 4);
      bw0[kt] = (v8h){(_Float16)a.x, (_Float16)a.y, (_Float16)a.z, (_Float16)a.w,
                      (_Float16)b.x, (_Float16)b.y, (_Float16)b.z, (_Float16)b.w};
      float4 cc = *(const float4*)(p1 + kt * 32);
      float4 d  = *(const float4*)(p1 + kt * 32 + 4);
      bw1[kt] = (v8h){(_Float16)cc.x, (_Float16)cc.y, (_Float16)cc.z, (_Float16)cc.w,
                      (_Float16)d.x, (_Float16)d.y, (_Float16)d.z, (_Float16)d.w};
    }
  }

  // ---- per-thread epilogue state: (eseq, colpair)
  const int eseq = tid >> 4;            // cluster member index 0..15
  const int ec0  = (tid & 15) * 2;
  const int ej   = slice * 32 + ec0;
  const int b0   = set * 32 + 2 * eseq;     // cluster 0: even ranks
  const int b1   = b0 + 1;                  // cluster 1: odd ranks

  float hr[2][2] = {{0.f, 0.f}, {0.f, 0.f}};
  const float br0 = bhh[ej];        const float br1 = bhh[ej + 1];
  const float bz0 = bhh[ej + 512];  const float bz1 = bhh[ej + 513];
  const float bn0 = bhh[ej + 1024]; const float bn1 = bhh[ej + 1025];
  const int mylen[2] = { lens[b0], lens[b1] };
  unsigned pg[2][3];
  {
    const _Float16* g0p = gx + (size_t)b0 * G3 + ej;
    pg[0][0] = *(const unsigned*)g0p;
    pg[0][1] = *(const unsigned*)(g0p + 512);
    pg[0][2] = *(const unsigned*)(g0p + 1024);
    const _Float16* g1p = gx + (size_t)b1 * G3 + ej;
    pg[1][0] = *(const unsigned*)g1p;
    pg[1][1] = *(const unsigned*)(g1p + 512);
    pg[1][2] = *(const unsigned*)(g1p + 1024);
  }
  __syncthreads();
  atomicMax(&sgl[0], mylen[0]);
  atomicMax(&sgl[1], mylen[1]);
  __syncthreads();
  const int glen0 = sgl[0];
  const int glen1 = sgl[1];
  const int gmax  = (glen0 > glen1) ? glen0 : glen1;

  const int arow = lane & 15;
  const int ak   = (lane >> 4) * 8;

  unsigned long long got[16];

  for (int t = 0; t < gmax; ++t) {
    if (t < glen0) PHASE(0)
    if (t < glen1) PHASE(1)
  }

  // ---- h_last ----
  {
    float* hl = out + (size_t)T_STEPS * BATCH * HID;
    *(float2*)(hl + (size_t)b0 * HID + ej) = make_float2(hr[0][0], hr[0][1]);
    *(float2*)(hl + (size_t)b1 * HID + ej) = make_float2(hr[1][0], hr[1][1]);
  }
}

// ---------------------------------------------------------------------------
extern "C" void kernel_launch(void* const* d_in, const int* in_sizes, int n_in,
                              void* d_out, int out_size, void* d_ws, size_t ws_size,
                              hipStream_t stream) {
  const float* x    = (const float*)d_in[0];
  const int*   lens = (const int*)d_in[1];
  const float* w_ih = (const float*)d_in[2];
  const float* w_hh = (const float*)d_in[3];
  const float* b_ih = (const float*)d_in[4];
  const float* b_hh = (const float*)d_in[5];
  float* out = (float*)d_out;

  // ws: gx f16 [65536][1536] = 192 MiB | hbuf u64[32768] = 256 KiB
  _Float16* gxbuf = (_Float16*)d_ws;
  unsigned long long* hbuf = (unsigned long long*)(gxbuf + (size_t)M_ROWS * G3);

  zero_hbuf<<<dim3((HB_U64 + 255) / 256), dim3(256), 0, stream>>>(hbuf);
  zero_out_tail<<<dim3(2048), dim3(256), 0, stream>>>(lens, out);
  gemm_gx<<<dim3(G3 / BN, M_ROWS / BM), dim3(256), 0, stream>>>(x, w_ih, b_ih, gxbuf);
  gru_scan3<<<dim3(32), dim3(256), 0, stream>>>(gxbuf, w_hh, lens, b_hh, out, hbuf);
}

// Round 2
// 4120.449 us; speedup vs baseline: 1.2773x; 1.2773x over previous
//
#include <hip/hip_runtime.h>

// (T,B,I,H) = (1024, 64, 512, 512)
#define T_STEPS 1024
#define BATCH   64
#define IN_F    512
#define HID     512
#define G3      1536
#define M_ROWS  (T_STEPS * BATCH)

#define NSLICE  16
#define NGROUP  16   // 16 groups of 4 seqs (hbuf layout identical to v2)
#define SPG     4
#define HB_U64  (2 * NGROUP * SPG * 256)   // ping-pong hbuf, u64 entries

typedef _Float16 v8h  __attribute__((ext_vector_type(8)));
typedef float    v4f  __attribute__((ext_vector_type(4)));

// ---------------------------------------------------------------------------
// gx = x * w_ih^T + b_ih -> f16 [65536][1536]   (unchanged, passing)
// ---------------------------------------------------------------------------
#define BM 64
#define BN 128
#define BK 32
#define LDP 40

__global__ __launch_bounds__(256) void gemm_gx(
    const float* __restrict__ X, const float* __restrict__ W,
    const float* __restrict__ bias, _Float16* __restrict__ C) {
  __shared__ _Float16 As[BM][LDP];
  __shared__ _Float16 Bs[BN][LDP];
  const int tid  = threadIdx.x;
  const int lane = tid & 63;
  const int wave = tid >> 6;
  const int m0 = blockIdx.y * BM;
  const int n0 = blockIdx.x * BN;

  v4f acc[8];
#pragma unroll
  for (int i = 0; i < 8; ++i) acc[i] = (v4f){0.f, 0.f, 0.f, 0.f};

  const int srow  = tid >> 2;
  const int kpart = (tid & 3) * 8;
  const int fr = lane & 15;
  const int ko = (lane >> 4) * 8;

  for (int kc = 0; kc < IN_F; kc += BK) {
    {
      const float* s = X + (size_t)(m0 + srow) * IN_F + kc + kpart;
      float4 a = *(const float4*)s;
      float4 b = *(const float4*)(s + 4);
      v8h o = {(_Float16)a.x, (_Float16)a.y, (_Float16)a.z, (_Float16)a.w,
               (_Float16)b.x, (_Float16)b.y, (_Float16)b.z, (_Float16)b.w};
      *(v8h*)&As[srow][kpart] = o;
    }
#pragma unroll
    for (int r = 0; r < 2; ++r) {
      const float* s = W + (size_t)(n0 + r * 64 + srow) * IN_F + kc + kpart;
      float4 a = *(const float4*)s;
      float4 b = *(const float4*)(s + 4);
      v8h o = {(_Float16)a.x, (_Float16)a.y, (_Float16)a.z, (_Float16)a.w,
               (_Float16)b.x, (_Float16)b.y, (_Float16)b.z, (_Float16)b.w};
      *(v8h*)&Bs[r * 64 + srow][kpart] = o;
    }
    __syncthreads();
    v8h af = *(const v8h*)&As[wave * 16 + fr][ko];
#pragma unroll
    for (int nt = 0; nt < 8; ++nt) {
      v8h bf = *(const v8h*)&Bs[nt * 16 + fr][ko];
      acc[nt] = __builtin_amdgcn_mfma_f32_16x16x32_f16(af, bf, acc[nt], 0, 0, 0);
    }
    __syncthreads();
  }

  const int rq = lane >> 4;
#pragma unroll
  for (int nt = 0; nt < 8; ++nt) {
    const int gcol = n0 + nt * 16 + fr;
    const float bv = bias[gcol];
#pragma unroll
    for (int r = 0; r < 4; ++r) {
      const int grow = m0 + wave * 16 + rq * 4 + r;
      C[(size_t)grow * G3 + gcol] = (_Float16)(acc[nt][r] + bv);
    }
  }
}

__global__ void zero_hbuf(unsigned long long* h) {
  const int i = blockIdx.x * 256 + threadIdx.x;
  if (i < HB_U64) h[i] = 0ull;
}

// Zero-pad out rows with t >= len[b] (scan does not write them).
__global__ __launch_bounds__(256) void zero_out_tail(const int* __restrict__ lens,
                                                     float* __restrict__ out) {
  __shared__ int slen[BATCH];
  if (threadIdx.x < BATCH) slen[threadIdx.x] = lens[threadIdx.x];
  __syncthreads();
  for (int row = blockIdx.x; row < T_STEPS * BATCH; row += gridDim.x) {
    const int t = row >> 6;
    const int b = row & 63;
    if (t < slen[b]) continue;
    float2* dst = (float2*)(out + (size_t)row * HID);
    dst[threadIdx.x] = make_float2(0.f, 0.f);
  }
}

// lgkm-only barrier: orders LDS, does NOT drain vmcnt -> advance polls stay
// in flight (in registers) across it.
static __device__ __forceinline__ void wg_barrier() {
  asm volatile("s_waitcnt lgkmcnt(0)" ::: "memory");
  __builtin_amdgcn_s_barrier();
  __builtin_amdgcn_sched_barrier(0);
}

// ---------------------------------------------------------------------------
// 2-chain interleaved persistent-weight GRU scan.
// 128 WGs = 16 slices x 8 pairs; pair p owns adjacent groups A=2p, B=2p+1
// (4 seqs each; adjacent => glens close => short solo tail). Phases alternate
// A(t), B(t), A(t+1)...: while one group's publish ages toward agent-scope
// visibility, the WG computes the other group's phase. Poll loads for phase
// k+1 are issued at the top of phase k into got[6] (12 VGPRs, no spill) and
// fly across lgkm-only barriers; at landing they are ~1 phase old.
// Both groups share h16[16][520]: A rows 0-3, B rows 4-7 (rows 8-15 zero) --
// the same 32 MFMAs/wave serve either phase; lane-range selects which gh is
// stored. Exchange protocol (tag-in-data u64, relaxed agent, ping-pong,
// v2-proven) unchanged; hbuf layout identical to v2.
// ---------------------------------------------------------------------------
#define PHASE(C)                                                               \
  {                                                                            \
    const int grpC = grp0 + C;                                                 \
    /* ---- land h(t) for group C (polls issued one phase ago) ---- */         \
    if (t > 0) {                                                               \
      const unsigned want = (unsigned)t;                                       \
      const unsigned long long* src =                                          \
          hbuf + (size_t)((t & 1) * NGROUP + grpC) * (SPG * 256);              \
      unsigned pend = (1u << nn) - 1u;                                         \
      _Pragma("unroll") for (int j = 0; j < 6; ++j)                            \
        if (j < nn && (unsigned)(got[j] >> 32) >= want) {                      \
          const int sq = ii[j] >> 8, jj = ii[j] & 255;                         \
          *(unsigned*)&h16[(C * 4 + sq) * 520 + jj * 2] = (unsigned)got[j];    \
          pend &= ~(1u << j);                                                  \
        }                                                                      \
      while (pend) {                                                           \
        __builtin_amdgcn_s_sleep(1);                                           \
        _Pragma("unroll") for (int j = 0; j < 6; ++j)                          \
          if (j < nn && (pend & (1u << j)))                                    \
            got[j] = __hip_atomic_load(src + ii[j], __ATOMIC_RELAXED,          \
                                       __HIP_MEMORY_SCOPE_AGENT);              \
        _Pragma("unroll") for (int j = 0; j < 6; ++j)                          \
          if (j < nn && (pend & (1u << j)) &&                                  \
              (unsigned)(got[j] >> 32) >= want) {                              \
            const int sq = ii[j] >> 8, jj = ii[j] & 255;                       \
            *(unsigned*)&h16[(C * 4 + sq) * 520 + jj * 2] = (unsigned)got[j];  \
            pend &= ~(1u << j);                                                \
          }                                                                    \
      }                                                                        \
    }                                                                          \
    /* ---- issue advance polls for the next phase ---- */                     \
    {                                                                          \
      int tn, cn;                                                              \
      if (C == 0) {                                                            \
        if (t < glenB) { tn = t; cn = 1; } else { tn = t + 1; cn = 0; }        \
      } else { tn = t + 1; cn = 0; }                                           \
      const int gln = (cn == 0) ? glenA : glenB;                               \
      if (tn >= 1 && tn < gln) {                                               \
        const unsigned long long* srcn =                                       \
            hbuf + (size_t)((tn & 1) * NGROUP + grp0 + cn) * (SPG * 256);      \
        _Pragma("unroll") for (int j = 0; j < 6; ++j)                          \
          if (j < nn)                                                          \
            got[j] = __hip_atomic_load(srcn + ii[j], __ATOMIC_RELAXED,         \
                                       __HIP_MEMORY_SCOPE_AGENT);              \
      }                                                                        \
    }                                                                          \
    wg_barrier(); /* h16 landing visible; advance polls stay in flight */      \
    /* ---- matvec: 32 MFMAs cover rows 0-15 (both groups) ---- */             \
    {                                                                          \
      v4f a0a = (v4f){0.f, 0.f, 0.f, 0.f}, a0b = a0a, a1a = a0a, a1b = a0a;    \
      _Pragma("unroll") for (int kt = 0; kt < 8; ++kt) {                       \
        v8h af = *(const v8h*)(hbase + kt * 32);                               \
        a0a = __builtin_amdgcn_mfma_f32_16x16x32_f16(af, bw0[kt], a0a, 0,0,0); \
        a1a = __builtin_amdgcn_mfma_f32_16x16x32_f16(af, bw1[kt], a1a, 0,0,0); \
      }                                                                        \
      _Pragma("unroll") for (int kt = 8; kt < 16; ++kt) {                      \
        v8h af = *(const v8h*)(hbase + kt * 32);                               \
        a0b = __builtin_amdgcn_mfma_f32_16x16x32_f16(af, bw0[kt], a0b, 0,0,0); \
        a1b = __builtin_amdgcn_mfma_f32_16x16x32_f16(af, bw1[kt], a1b, 0,0,0); \
      }                                                                        \
      v4f acc0 = a0a + a0b;                                                    \
      v4f acc1 = a1a + a1b;                                                    \
      if ((lane >> 4) == C) { /* C=0: lanes 0-15 (rows 0-3); C=1: 16-31 */     \
        *(v4f*)&ghl[(w * 32 + (lane & 15)) * 4]      = acc0;                   \
        *(v4f*)&ghl[(w * 32 + 16 + (lane & 15)) * 4] = acc1;                   \
      }                                                                        \
    }                                                                          \
    wg_barrier(); /* ghl visible to epilogue */                                \
    /* ---- epilogue: tid<64, one (seq, colpair) each ---- */                  \
    if (tid < 64) {                                                            \
      const float ar0 = ghl[(0 * 32 + ec0) * 4 + es];                          \
      const float ar1 = ghl[(0 * 32 + ec0 + 1) * 4 + es];                      \
      const float az0 = ghl[(1 * 32 + ec0) * 4 + es];                          \
      const float az1 = ghl[(1 * 32 + ec0 + 1) * 4 + es];                      \
      const float an0 = ghl[(2 * 32 + ec0) * 4 + es];                          \
      const float an1 = ghl[(2 * 32 + ec0 + 1) * 4 + es];                      \
      union { unsigned u; _Float16 h[2]; } g0, g1, g2, pk;                     \
      g0.u = pg[C][0]; g1.u = pg[C][1]; g2.u = pg[C][2];                       \
      const int bq = grpC * 4 + es;                                            \
      float h0 = hr[C][0], h1 = hr[C][1];                                      \
      const bool act = (t < mylen[C]);                                         \
      if (act) {                                                               \
        const float r0 = 1.f / (1.f + __expf(-((float)g0.h[0] + ar0 + br0)));  \
        const float z0 = 1.f / (1.f + __expf(-((float)g1.h[0] + az0 + bz0)));  \
        const float p0 = (float)g2.h[0] + r0 * (an0 + bn0);                    \
        const float n0v = 1.f - 2.f / (__expf(2.f * p0) + 1.f);                \
        h0 = (1.f - z0) * n0v + z0 * h0;                                       \
        const float r1 = 1.f / (1.f + __expf(-((float)g0.h[1] + ar1 + br1)));  \
        const float z1 = 1.f / (1.f + __expf(-((float)g1.h[1] + az1 + bz1)));  \
        const float p1 = (float)g2.h[1] + r1 * (an1 + bn1);                    \
        const float n1v = 1.f - 2.f / (__expf(2.f * p1) + 1.f);                \
        h1 = (1.f - z1) * n1v + z1 * h1;                                       \
        hr[C][0] = h0; hr[C][1] = h1;                                          \
      }                                                                        \
      /* publish first (peers' critical path), then out-store, then prefetch */\
      pk.h[0] = (_Float16)h0; pk.h[1] = (_Float16)h1;                          \
      const unsigned long long pv =                                            \
          ((unsigned long long)(unsigned)(t + 1) << 32) | pk.u;                \
      const size_t di = (size_t)(((t + 1) & 1) * NGROUP + grpC) * (SPG * 256)  \
                        + (size_t)es * 256 + slice * 16 + (tid & 15);          \
      __hip_atomic_store(hbuf + di, pv, __ATOMIC_RELAXED,                      \
                         __HIP_MEMORY_SCOPE_AGENT);                            \
      if (act) {                                                               \
        float* o = out + (size_t)t * (BATCH * HID) + (size_t)bq * HID + ej;    \
        *(float2*)o = make_float2(h0, h1);                                     \
      }                                                                        \
      const int gcl = (C == 0) ? glenA : glenB;                                \
      const int tn2 = (t + 1 < gcl) ? t + 1 : t;                               \
      const _Float16* gxr = gx + ((size_t)tn2 * BATCH + bq) * G3 + ej;         \
      pg[C][0] = *(const unsigned*)gxr;                                        \
      pg[C][1] = *(const unsigned*)(gxr + 512);                                \
      pg[C][2] = *(const unsigned*)(gxr + 1024);                               \
    }                                                                          \
  }

__global__ __launch_bounds__(192, 1) void gru_scan4(
    const _Float16* __restrict__ gx, const float* __restrict__ whh,
    const int* __restrict__ lens, const float* __restrict__ bhh,
    float* __restrict__ out, unsigned long long* hbuf) {
  const int bid   = blockIdx.x;      // 128 WGs
  const int slice = bid & 15;
  const int pair  = bid >> 4;        // 0..7
  const int grp0  = pair * 2;
  const int tid  = threadIdx.x;
  const int lane = tid & 63;
  const int w    = tid >> 6;         // wave = gate (0:r 1:z 2:n)

  __shared__ __align__(16) _Float16 h16[16 * 520];  // rows 0-3: A, 4-7: B
  __shared__ __align__(16) float ghl[3 * 32 * 4];   // [gate][col][seq]

  for (int i = tid; i < 16 * 520 / 2; i += 192) ((unsigned*)h16)[i] = 0u;

  // ---- persistent weight B-frags: wave w, rows w*512 + slice*32 + [0,32)
  v8h bw0[16], bw1[16];
  {
    const int r15 = lane & 15;
    const int k8  = (lane >> 4) * 8;
    const float* p0 = whh + (size_t)(w * 512 + slice * 32 + r15) * HID + k8;
    const float* p1 = p0 + 16 * HID;
#pragma unroll
    for (int kt = 0; kt < 16; ++kt) {
      float4 a = *(const float4*)(p0 + kt * 32);
      float4 b = *(const float4*)(p0 + kt * 32 + 4);
      bw0[kt] = (v8h){(_Float16)a.x, (_Float16)a.y, (_Float16)a.z, (_Float16)a.w,
                      (_Float16)b.x, (_Float16)b.y, (_Float16)b.z, (_Float16)b.w};
      float4 c = *(const float4*)(p1 + kt * 32);
      float4 d = *(const float4*)(p1 + kt * 32 + 4);
      bw1[kt] = (v8h){(_Float16)c.x, (_Float16)c.y, (_Float16)c.z, (_Float16)c.w,
                      (_Float16)d.x, (_Float16)d.y, (_Float16)d.z, (_Float16)d.w};
    }
  }

  // ---- epilogue thread state: tid<64 owns (seq = tid>>4, cols ec0,ec0+1)
  const int es  = tid >> 4;
  const int ec0 = (tid & 15) * 2;
  const int ej  = slice * 32 + ec0;
  float hr[2][2] = {{0.f, 0.f}, {0.f, 0.f}};
  float br0 = 0, br1 = 0, bz0 = 0, bz1 = 0, bn0 = 0, bn1 = 0;
  int mylen[2] = {0, 0};
  unsigned pg[2][3];
  if (tid < 64) {
    br0 = bhh[ej];        br1 = bhh[ej + 1];
    bz0 = bhh[ej + 512];  bz1 = bhh[ej + 513];
    bn0 = bhh[ej + 1024]; bn1 = bhh[ej + 1025];
    mylen[0] = lens[grp0 * 4 + es];
    mylen[1] = lens[grp0 * 4 + 4 + es];
    const _Float16* g0p = gx + (size_t)(grp0 * 4 + es) * G3 + ej;
    pg[0][0] = *(const unsigned*)g0p;
    pg[0][1] = *(const unsigned*)(g0p + 512);
    pg[0][2] = *(const unsigned*)(g0p + 1024);
    const _Float16* g1p = gx + (size_t)(grp0 * 4 + 4 + es) * G3 + ej;
    pg[1][0] = *(const unsigned*)g1p;
    pg[1][1] = *(const unsigned*)(g1p + 512);
    pg[1][2] = *(const unsigned*)(g1p + 1024);
  }
  const int ba = grp0 * 4;
  const int glenA = max(max(lens[ba], lens[ba + 1]), max(lens[ba + 2], lens[ba + 3]));
  const int glenB = max(max(lens[ba + 4], lens[ba + 5]), max(lens[ba + 6], lens[ba + 7]));
  __syncthreads();

  const int arow = lane & 15;
  const int ak   = (lane >> 4) * 8;
  const _Float16* hbase = &h16[arow * 520 + ak];

  // pull-set indices (<=6 of the group's 1024 u64s; same for both groups)
  int ii[6]; int nn = 0;
  for (int i = tid; i < SPG * 256; i += 192) { ii[nn] = i; ++nn; }

  unsigned long long got[6];

  for (int t = 0; t < glenA; ++t) {
    PHASE(0)
    if (t < glenB) PHASE(1)
  }

  if (tid < 64) {
    float* hl = out + (size_t)T_STEPS * BATCH * HID;
    *(float2*)(hl + (size_t)(grp0 * 4 + es) * HID + ej)     = make_float2(hr[0][0], hr[0][1]);
    *(float2*)(hl + (size_t)(grp0 * 4 + 4 + es) * HID + ej) = make_float2(hr[1][0], hr[1][1]);
  }
}

// ---------------------------------------------------------------------------
extern "C" void kernel_launch(void* const* d_in, const int* in_sizes, int n_in,
                              void* d_out, int out_size, void* d_ws, size_t ws_size,
                              hipStream_t stream) {
  const float* x    = (const float*)d_in[0];
  const int*   lens = (const int*)d_in[1];
  const float* w_ih = (const float*)d_in[2];
  const float* w_hh = (const float*)d_in[3];
  const float* b_ih = (const float*)d_in[4];
  const float* b_hh = (const float*)d_in[5];
  float* out = (float*)d_out;

  // ws: gx f16 [65536][1536] = 192 MiB | hbuf u64[32768] = 256 KiB
  _Float16* gxbuf = (_Float16*)d_ws;
  unsigned long long* hbuf = (unsigned long long*)(gxbuf + (size_t)M_ROWS * G3);

  zero_hbuf<<<dim3((HB_U64 + 255) / 256), dim3(256), 0, stream>>>(hbuf);
  zero_out_tail<<<dim3(2048), dim3(256), 0, stream>>>(lens, out);
  gemm_gx<<<dim3(G3 / BN, M_ROWS / BM), dim3(256), 0, stream>>>(x, w_ih, b_ih, gxbuf);
  gru_scan4<<<dim3(NSLICE * 8), dim3(192), 0, stream>>>(
      gxbuf, w_hh, lens, b_hh, out, hbuf);
}